// Round 4
// baseline (495.513 us; speedup 1.0000x reference)
//
#include <hip/hip_runtime.h>

// adder2d: out[b,f,l] = -sum_k |W[f,k] - P[b,k,l]|, P = 3x3/s1/p1 im2col of x.
// Round-4 redesign: zero-LDS, zero-barrier, single-wave (64-thread) blocks.
// lane = one m; wave owns 16 filters x K/4. P taps live in registers
// (double-buffered pa/pb across chunks, masked-safe addresses * {0,1}).
// W addresses are blockIdx+constant only -> uniform -> s_load into SGPRs;
// inner op: v_sub_f32 d, sW, vP ; v_add_f32 acc, acc, |d|  (2 inst/elem).
// Grid 196 x 8 x 4 = 6272 one-wave blocks (6.125/SIMD). K-split x4 into
// d_ws slabs + unchanged combine kernel.

#define B_    16
#define C_    128
#define HH    28
#define WW    28
#define F_    128
#define L_    (HH * WW)          // 784
#define K_    (C_ * 9)           // 1152
#define M_    (B_ * L_)          // 12544 = 196 * 64 exactly
#define NFW   16                 // filters per wave/block
#define FG    (F_ / NFW)         // 8 f-groups
#define BC    4                  // channels per chunk
#define KC    (BC * 9)           // 36 k per chunk
#define SPLIT 4
#define SLAB  (B_ * F_ * L_)     // 1,605,632 floats per partial slab
#define NMT   (M_ / 64)          // 196 m-tiles

__global__ __launch_bounds__(64, 2)
void adder2d_main(const float* __restrict__ x, const float* __restrict__ Wg,
                  float* __restrict__ dst, int nch, int direct) {
    const int lane = threadIdx.x;             // 0..63, = m within tile
    const int mt = blockIdx.x;
    const int fg = blockIdx.y;
    const int sp = blockIdx.z;

    const int m  = mt * 64 + lane;
    const int b  = m / L_;
    const int l  = m - b * L_;
    const int ho = l / WW;
    const int wo = l - ho * WW;

    // Per-lane tap offsets (element units within a channel plane) + 0/1 mask.
    // Invalid taps read offset 0 (safe, in-bounds) and are zeroed by fm.
    int   toff[9];
    float fm[9];
    #pragma unroll
    for (int r = 0; r < 9; ++r) {
        const int dy = r / 3 - 1;
        const int dx = r - (r / 3) * 3 - 1;
        const bool ok = ((unsigned)(ho + dy) < (unsigned)HH) &&
                        ((unsigned)(wo + dx) < (unsigned)WW);
        toff[r] = ok ? (dy * WW + dx) : 0;
        fm[r]   = ok ? 1.0f : 0.0f;
    }
    const float* xb = x + (size_t)b * (C_ * L_) + l;   // per-lane base (c=0 plane)
    const int c0 = sp * nch * BC;                      // first channel of split

    float acc[NFW];
    #pragma unroll
    for (int j = 0; j < NFW; ++j) acc[j] = 0.0f;

    // W row base for this f-group: uniform (blockIdx-only) -> s_load path.
    const float* Wf = Wg + (size_t)(fg * NFW) * K_;

    // ---- helpers (all constant-indexed; arrays must stay in VGPRs) ----
    auto load_chunk = [&](float (&pv)[KC], int c8) {
        const float* xc = xb + (size_t)c8 * L_;
        #pragma unroll
        for (int c = 0; c < BC; ++c)
            #pragma unroll
            for (int r = 0; r < 9; ++r)
                pv[c * 9 + r] = xc[c * L_ + toff[r]];
    };
    auto mask_chunk = [&](float (&pv)[KC]) {
        #pragma unroll
        for (int c = 0; c < BC; ++c)
            #pragma unroll
            for (int r = 0; r < 9; ++r)
                pv[c * 9 + r] *= fm[r];
    };
    auto compute_chunk = [&](const float (&pm)[KC], int c8) {
        const float* Wk = Wf + c8 * 9;        // uniform: W[fg*16 + j][c8*9 + kk]
        #pragma unroll
        for (int kw = 0; kw < KC / 2; ++kw) { // 2-k windows: 32 SGPRs live
            float w0[NFW], w1[NFW];
            #pragma unroll
            for (int j = 0; j < NFW; ++j) {
                w0[j] = Wk[j * K_ + 2 * kw];
                w1[j] = Wk[j * K_ + 2 * kw + 1];
            }
            #pragma unroll
            for (int j = 0; j < NFW; ++j) {
                acc[j] += __builtin_fabsf(pm[2 * kw]     - w0[j]);
                acc[j] += __builtin_fabsf(pm[2 * kw + 1] - w1[j]);
            }
        }
    };

    // ---- ping-pong main loop: loads of next chunk in flight over compute ----
    float pa[KC], pb[KC];
    load_chunk(pa, c0);
    const int npair = nch >> 1;               // nch is even (8 or 32)
    #pragma unroll 1
    for (int pr = 0; pr < npair; ++pr) {
        const int cA = c0 + (2 * pr) * BC;
        const int cB = cA + BC;
        load_chunk(pb, cB);                   // issue B loads (in flight)
        mask_chunk(pa);                       // waits only A's loads
        compute_chunk(pa, cA);
        if (pr + 1 < npair) load_chunk(pa, cB + BC);  // issue next A
        mask_chunk(pb);
        compute_chunk(pb, cB);
    }

    // ---- store 16 filters (lane-coalesced over l; slab or direct) ----
    float* o = (direct ? dst : dst + (size_t)sp * SLAB)
               + ((size_t)b * F_ + fg * NFW) * L_ + l;
    const float sgn = direct ? -1.0f : 1.0f;
    #pragma unroll
    for (int j = 0; j < NFW; ++j)
        o[(size_t)j * L_] = sgn * acc[j];
}

__global__ __launch_bounds__(256)
void adder2d_combine(const float* __restrict__ ws, float* __restrict__ out) {
    const int i = blockIdx.x * 256 + threadIdx.x;     // float4 index, SLAB/4 total
    const float4* a0 = (const float4*)ws;
    const float4* a1 = (const float4*)(ws + SLAB);
    const float4* a2 = (const float4*)(ws + 2 * (size_t)SLAB);
    const float4* a3 = (const float4*)(ws + 3 * (size_t)SLAB);
    float4 p0 = a0[i], p1 = a1[i], p2 = a2[i], p3 = a3[i];
    float4 r;
    r.x = -((p0.x + p1.x) + (p2.x + p3.x));
    r.y = -((p0.y + p1.y) + (p2.y + p3.y));
    r.z = -((p0.z + p1.z) + (p2.z + p3.z));
    r.w = -((p0.w + p1.w) + (p2.w + p3.w));
    ((float4*)out)[i] = r;
}

extern "C" void kernel_launch(void* const* d_in, const int* in_sizes, int n_in,
                              void* d_out, int out_size, void* d_ws, size_t ws_size,
                              hipStream_t stream) {
    const float* x = (const float*)d_in[0];   // [16,128,28,28]
    const float* W = (const float*)d_in[1];   // [128,128,3,3]
    float* out = (float*)d_out;               // [16,128,28,28]
    float* ws  = (float*)d_ws;

    const size_t needed = (size_t)SPLIT * SLAB * sizeof(float);  // ~25.7 MB
    if (ws_size >= needed) {
        dim3 grid(NMT, FG, SPLIT);            // (196, 8, 4) = 6272 one-wave blocks
        adder2d_main<<<grid, 64, 0, stream>>>(x, W, ws, (C_ / BC) / SPLIT, 0);
        adder2d_combine<<<SLAB / 4 / 256, 256, 0, stream>>>(ws, out);
    } else {
        dim3 grid(NMT, FG, 1);                // fallback: direct, full K
        adder2d_main<<<grid, 64, 0, stream>>>(x, W, out, C_ / BC, 1);
    }
}

// Round 5
// 209.240 us; speedup vs baseline: 2.3682x; 2.3682x over previous
//
#include <hip/hip_runtime.h>

// adder2d: out[b,f,l] = -sum_k |W[f,k] - P[b,k,l]|, P = 3x3/s1/p1 im2col of x.
// Round-5: 1-wave (64-thread) blocks, zero barriers. Tile 64m x 64f, each
// thread 8m x 8f (64 acc), k-loop reads 4x ds_read_b128 per thread-k
// (16 elems/read -> LDS:VALU = 0.75, was 1.125). Grid 196x2x4 = 1568
// one-wave blocks (6.125/CU, 87.5% balance ceiling, was 76.6%).
// P prefetched global->regs (masked taps), W staged per-chunk via per-lane
// float4 row loads (L2-hot) -> LDS. Single wave => DS program order, no
// __syncthreads, no vmcnt drain. K-split x4 slabs + combine unchanged.

#define B_    16
#define C_    128
#define HH    28
#define WW    28
#define F_    128
#define L_    (HH * WW)          // 784
#define K_    (C_ * 9)           // 1152
#define M_    (B_ * L_)          // 12544 = 196 * 64 exactly
#define TM    64
#define TF    64
#define FG    (F_ / TF)          // 2 f-groups
#define BC    4                  // channels per chunk
#define KC    (BC * 9)           // 36 k per chunk
#define SPLIT 4
#define SLAB  (B_ * F_ * L_)     // 1,605,632 floats per partial slab
#define NMT   (M_ / TM)          // 196 m-tiles

__global__ __launch_bounds__(64, 2)
void adder2d_main(const float* __restrict__ x, const float* __restrict__ Wg,
                  float* __restrict__ dst, int nch, int direct) {
    __shared__ __align__(16) float Pl[KC][TM];   // 9216 B, no pad needed
    __shared__ __align__(16) float Wl[KC][TF];   // 9216 B

    const int t  = threadIdx.x;        // 0..63
    const int tx = t & 7;              // m-group: 8 m each
    const int ty = t >> 3;             // f-group: 8 f each
    const int mt = blockIdx.x, fg = blockIdx.y, sp = blockIdx.z;
    const int f0 = fg * TF;
    const int c0 = sp * nch * BC;      // first channel of this split

    // ---- staging identity: lane t stages m = mt*64 + t and W row f0 + t ----
    const int m  = mt * TM + t;
    const int b  = m / L_;
    const int l  = m - b * L_;
    const int ho = l / WW, wo = l - ho * WW;
    int   toff[9];
    float fm[9];
    #pragma unroll
    for (int r = 0; r < 9; ++r) {
        const int dy = r / 3 - 1;
        const int dx = r - (r / 3) * 3 - 1;
        const bool ok = ((unsigned)(ho + dy) < (unsigned)HH) &&
                        ((unsigned)(wo + dx) < (unsigned)WW);
        toff[r] = ok ? (dy * WW + dx) : 0;   // safe addr, zeroed by fm
        fm[r]   = ok ? 1.0f : 0.0f;
    }
    const float* xb   = x + (size_t)b * (C_ * L_) + l;
    const float* wrow = Wg + (size_t)(f0 + t) * K_;   // per-lane W row (vector path)

    float acc[8][8];
    #pragma unroll
    for (int i = 0; i < 8; ++i)
        #pragma unroll
        for (int j = 0; j < 8; ++j) acc[i][j] = 0.0f;

    // ---- prologue: prefetch P chunk 0 into regs ----
    float pp[KC];
    {
        const float* xc = xb + (size_t)c0 * L_;
        #pragma unroll
        for (int c = 0; c < BC; ++c)
            #pragma unroll
            for (int r = 0; r < 9; ++r)
                pp[c * 9 + r] = xc[c * L_ + toff[r]];
    }

    #pragma unroll 1
    for (int ch = 0; ch < nch; ++ch) {
        const int c8 = c0 + ch * BC;
        // ---- stage W: per-lane float4 row loads (L2-hot), scatter to Wl[k][t]
        {
            const float4* wr = (const float4*)(wrow + (size_t)c8 * 9);
            #pragma unroll
            for (int i = 0; i < 9; ++i) {
                const float4 wv = wr[i];
                Wl[4 * i + 0][t] = wv.x;
                Wl[4 * i + 1][t] = wv.y;
                Wl[4 * i + 2][t] = wv.z;
                Wl[4 * i + 3][t] = wv.w;
            }
        }
        // ---- stage P from prefetch regs (masked)
        #pragma unroll
        for (int c = 0; c < BC; ++c)
            #pragma unroll
            for (int r = 0; r < 9; ++r)
                Pl[c * 9 + r][t] = pp[c * 9 + r] * fm[r];
        // ---- prefetch next chunk P (in flight across the whole compute)
        if (ch + 1 < nch) {
            const float* xc = xb + (size_t)(c8 + BC) * L_;
            #pragma unroll
            for (int c = 0; c < BC; ++c)
                #pragma unroll
                for (int r = 0; r < 9; ++r)
                    pp[c * 9 + r] = xc[c * L_ + toff[r]];
        }
        // ---- compute: single wave => DS ops ordered by lgkmcnt, no barrier
        #pragma unroll 4
        for (int k = 0; k < KC; ++k) {
            const float4 pA = *(const float4*)&Pl[k][tx * 8];
            const float4 pB = *(const float4*)&Pl[k][tx * 8 + 4];
            const float4 wA = *(const float4*)&Wl[k][ty * 8];
            const float4 wB = *(const float4*)&Wl[k][ty * 8 + 4];
            const float pm[8] = {pA.x, pA.y, pA.z, pA.w, pB.x, pB.y, pB.z, pB.w};
            const float wn[8] = {wA.x, wA.y, wA.z, wA.w, wB.x, wB.y, wB.z, wB.w};
            #pragma unroll
            for (int i = 0; i < 8; ++i)
                #pragma unroll
                for (int j = 0; j < 8; ++j)
                    acc[i][j] += __builtin_fabsf(pm[i] - wn[j]);
        }
    }

    // ---- store: thread covers m = mt*64 + tx*8 .. +8 (same image: 8 | 784)
    const int mb = mt * TM + tx * 8;
    const int bI = mb / L_;
    const int lb = mb - bI * L_;
    float* slab = direct ? dst : dst + (size_t)sp * SLAB;
    const float sgn = direct ? -1.0f : 1.0f;
    #pragma unroll
    for (int j = 0; j < 8; ++j) {
        const int f = f0 + ty * 8 + j;
        float* o = &slab[(size_t)(bI * F_ + f) * L_ + lb];
        *(float4*)o       = make_float4(sgn * acc[0][j], sgn * acc[1][j],
                                        sgn * acc[2][j], sgn * acc[3][j]);
        *(float4*)(o + 4) = make_float4(sgn * acc[4][j], sgn * acc[5][j],
                                        sgn * acc[6][j], sgn * acc[7][j]);
    }
}

__global__ __launch_bounds__(256)
void adder2d_combine(const float* __restrict__ ws, float* __restrict__ out) {
    const int i = blockIdx.x * 256 + threadIdx.x;     // float4 index, SLAB/4 total
    const float4* a0 = (const float4*)ws;
    const float4* a1 = (const float4*)(ws + SLAB);
    const float4* a2 = (const float4*)(ws + 2 * (size_t)SLAB);
    const float4* a3 = (const float4*)(ws + 3 * (size_t)SLAB);
    float4 p0 = a0[i], p1 = a1[i], p2 = a2[i], p3 = a3[i];
    float4 r;
    r.x = -((p0.x + p1.x) + (p2.x + p3.x));
    r.y = -((p0.y + p1.y) + (p2.y + p3.y));
    r.z = -((p0.z + p1.z) + (p2.z + p3.z));
    r.w = -((p0.w + p1.w) + (p2.w + p3.w));
    ((float4*)out)[i] = r;
}

extern "C" void kernel_launch(void* const* d_in, const int* in_sizes, int n_in,
                              void* d_out, int out_size, void* d_ws, size_t ws_size,
                              hipStream_t stream) {
    const float* x = (const float*)d_in[0];   // [16,128,28,28]
    const float* W = (const float*)d_in[1];   // [128,128,3,3]
    float* out = (float*)d_out;               // [16,128,28,28]
    float* ws  = (float*)d_ws;

    const size_t needed = (size_t)SPLIT * SLAB * sizeof(float);  // ~25.7 MB
    if (ws_size >= needed) {
        dim3 grid(NMT, FG, SPLIT);            // (196, 2, 4) = 1568 one-wave blocks
        adder2d_main<<<grid, 64, 0, stream>>>(x, W, ws, (C_ / BC) / SPLIT, 0);
        adder2d_combine<<<SLAB / 4 / 256, 256, 0, stream>>>(ws, out);
    } else {
        dim3 grid(NMT, FG, 1);                // fallback: direct, full K
        adder2d_main<<<grid, 64, 0, stream>>>(x, W, out, C_ / BC, 1);
    }
}